// Round 1
// 455.752 us; speedup vs baseline: 1.0430x; 1.0430x over previous
//
#include <hip/hip_runtime.h>

#define NODE 8192
#define FEAT 64
#define OUTD 64
#define NCOL 256  // BATCH*OUTD

typedef float f32x4 __attribute__((ext_vector_type(4)));
typedef short s16x8 __attribute__((ext_vector_type(8)));
typedef short s16x4 __attribute__((ext_vector_type(4)));
typedef int   i32x4 __attribute__((ext_vector_type(4)));

__device__ __forceinline__ short f2bf(float f) {
    // round-to-nearest-even fp32 -> bf16 (finite inputs)
    unsigned u = __builtin_bit_cast(unsigned, f);
    u += 0x7FFFu + ((u >> 16) & 1u);
    return (short)(u >> 16);
}

__device__ __forceinline__ s16x4 cvt4(const f32x4& v) {
    s16x4 r;
#pragma unroll
    for (int i = 0; i < 4; ++i) r[i] = f2bf(v[i]);
    return r;
}

// ---------------------------------------------------------------------------
// k0: bias2[o] = b_out[o] + sum_f nl_b[f] * w_out[o,f]
// ---------------------------------------------------------------------------
__global__ void bias2_kernel(const float* __restrict__ nl_b,
                             const float* __restrict__ w_out,
                             const float* __restrict__ b_out,
                             float* __restrict__ bias2) {
    __shared__ float part[4][64];
    const int o = threadIdx.x & 63;
    const int fc = threadIdx.x >> 6;
    float s = 0.f;
#pragma unroll
    for (int i = 0; i < 16; ++i) {
        int f = fc * 16 + i;
        s += nl_b[f] * w_out[o * FEAT + f];
    }
    part[fc][o] = s;
    __syncthreads();
    if (fc == 0)
        bias2[o] = b_out[o] + part[0][o] + part[1][o] + part[2][o] + part[3][o];
}

// ---------------------------------------------------------------------------
// k0b: out[b,i,o] = bias2[o]  (gemm K-split accumulates via atomicAdd on top)
// ---------------------------------------------------------------------------
__global__ __launch_bounds__(256) void init_out_kernel(
    float* __restrict__ out, const float* __restrict__ bias2) {
    const int idx = (int)blockIdx.x * 256 + threadIdx.x;
    f32x4 bv = *(const f32x4*)(bias2 + ((idx & 15) << 2));
    *(f32x4*)(out + (size_t)idx * 4) = bv;
}

// ---------------------------------------------------------------------------
// k1 (REWRITTEN): Ybf[c,jn] = sum_f (inv_sqrt2*nl_w[f]*w_out[o,f]) * x[b,jn,f]
// written in the gemm's swizzled B-fragment layout:
//   flat = (c16*256 + kb)*512 + q*128 + e + (c&15)*8,  kb=jn>>5, q=(jn>>3)&3,
//   e=jn&7.
// Old version: 1088 scalar LDS reads + 16 scattered 2B stores per thread.
// New: block = (batch b, 128 nodes); thread owns a 4-o x 8-jn register tile.
//   Per f: 8 x-reads (b32, 16-lane broadcast, banks {0,8,16,24}+c -> no
//   conflict at stride 65) + 1 w2t b128 + 32 fmac.  Stores: the thread's
//   (c&15)*8 positions for its 4 consecutive o and 8 consecutive jn are
//   CONTIGUOUS 64B -> 4x coalesced s16x8 stores.  ~6 us predicted.
// ---------------------------------------------------------------------------
__global__ __launch_bounds__(256) void build_ybf_kernel(
    const float* __restrict__ x, const float* __restrict__ nl_w,
    const float* __restrict__ w_out, unsigned short* __restrict__ ybf) {
    __shared__ float xs[128 * 65];   // [jl][f], stride 65
    __shared__ float w2t[64 * 68];   // [f][o],  stride 68 (16B-aligned rows)
    const int tid = threadIdx.x;
    const int b   = (int)blockIdx.x >> 6;        // 4 batches
    const int j0  = ((int)blockIdx.x & 63) << 7; // 64 groups of 128 nodes

    // stage x tile (128 x 64 fp32, coalesced f32x4)
    const f32x4* src = (const f32x4*)(x + ((size_t)b * NODE + j0) * FEAT);
#pragma unroll
    for (int it = 0; it < 8; ++it) {
        int i = tid + it * 256;
        f32x4 v = src[i];
        int jl = i >> 4, f0 = (i & 15) << 2;
        float* d = &xs[jl * 65 + f0];
        d[0] = v[0]; d[1] = v[1]; d[2] = v[2]; d[3] = v[3];
    }
    // stage scaled W2 transposed: w2t[f][o]
#pragma unroll
    for (int it = 0; it < 16; ++it) {
        int i = tid + it * 256;
        int o = i >> 6, f = i & 63;
        w2t[f * 68 + o] = w_out[i] * (0.70710678118654752f * nl_w[f]);
    }
    __syncthreads();

    const int oq = tid & 15;  // o = oq*4 + i, i=0..3
    const int J  = tid >> 4;  // jn = j0 + J*8 + e, e=0..7
    const float* xr = &xs[(J * 8) * 65];
    const float* wr = &w2t[oq * 4];

    float acc[4][8];
#pragma unroll
    for (int i = 0; i < 4; ++i)
#pragma unroll
        for (int e = 0; e < 8; ++e) acc[i][e] = 0.f;

#pragma unroll 4
    for (int f = 0; f < 64; ++f) {
        f32x4 w4 = *(const f32x4*)(wr + f * 68);
        float xv[8];
#pragma unroll
        for (int e = 0; e < 8; ++e) xv[e] = xr[e * 65 + f];
#pragma unroll
        for (int i = 0; i < 4; ++i)
#pragma unroll
            for (int e = 0; e < 8; ++e) acc[i][e] += w4[i] * xv[e];
    }

    // swizzled store: c = b*64 + oq*4 + i ; jn = j0 + J*8 + e
    const int jn0 = j0 + J * 8;
    const int kb  = jn0 >> 5;
    const int q   = (jn0 >> 3) & 3;
    const int c16 = b * 4 + (oq >> 2);
    unsigned short* dst = ybf + ((size_t)(c16 * 256 + kb) * 512) +
                          q * 128 + ((oq & 3) * 4) * 8;
#pragma unroll
    for (int i = 0; i < 4; ++i) {
        s16x8 pv;
#pragma unroll
        for (int e = 0; e < 8; ++e) pv[e] = f2bf(acc[i][e]);
        *(s16x8*)(dst + i * 8) = pv;
    }
}

// ---------------------------------------------------------------------------
// k2: out += adj @ Y.  1024 blocks x 256 thr.
// CO-XCD DECODE (this round's change): HW dispatch sends block bi to XCD
// bi&7.  Old decode (rg=bi>>3) put the blocks sharing one 128-row adj slice
// on 8 DIFFERENT (non-coherent) L2s -> FETCH_SIZE = 2.15x adj.  New decode:
//   xcd=bi&7, seq=bi>>3, rg=(seq>>4)*8+xcd, cg=(seq>>2)&3, ks=seq&3
// -> all 16 sharers (4cg x 4ks) of a rowgroup run concurrently on ONE XCD;
// the 4 cg sharing each (rg,ks) 1MB slice dedup in that XCD's 4MB L2.
// K-split widened 2->4: adj still fetched once, occupancy 2 -> 3-4 blocks/CU
// (LDS 40KB) for latency hiding.  Kernel body unchanged: barrier-free
// private-LDS 4-slot pipeline (R3 post-mortem: no __syncthreads in K-loop),
// load->use distance 4-6 rounds, LDS row stride 40 elts (conflict-free b128).
// Epilogue: fp32 atomicAdd (out pre-init to bias2); the 4 ks-sharers of an
// out cell are co-XCD -> L2-local atomics.
// ---------------------------------------------------------------------------
__global__ __launch_bounds__(256, 2) void gemm_adj_kernel(
    const float* __restrict__ adj, const unsigned short* __restrict__ ybf,
    float* __restrict__ out) {
    // per-wave: 4 bufs x 32 rows x 40 elts bf16 = 10KB; 4 waves = 40KB
    __shared__ __align__(16) unsigned short As[4][4][32 * 40];

    const int tid  = threadIdx.x;
    const int lane = tid & 63;
    const int wv   = tid >> 6;
    const int bi   = (int)blockIdx.x;
    const int xcd  = bi & 7;
    const int seq  = bi >> 3;
    const int rg   = (seq >> 4) * 8 + xcd;  // 64 rowgroups of 128 rows
    const int cg   = (seq >> 2) & 3;        // batch
    const int ks   = seq & 3;               // K-quarter (2048)
    const int row0 = rg * 128 + wv * 32;
    const int t16  = lane & 15;
    const int quad = lane >> 4;
    const int sr   = lane >> 2;  // staging row within 16-group
    const int sc   = lane & 3;   // staging 16B chunk

    // A staging pointers: per inst (g,j): 16 rows x 64B fully coalesced
    const float* aGr[2];
    aGr[0] = adj + (size_t)(row0 + sr) * NODE + ks * 2048 + sc * 4;
    aGr[1] = aGr[0] + (size_t)16 * NODE;

    // B fragment pointers (swizzled Ybf): frag (nt, tile) = bpB[nt] + tile*512
    const unsigned short* bpB[4];
#pragma unroll
    for (int nt = 0; nt < 4; ++nt)
        bpB[nt] = ybf + ((size_t)((cg * 4 + nt) * 256 + ks * 64) * 512) + lane * 8;

    unsigned short* Aw = &As[wv][0][0];
    const int woff = sr * 40 + sc * 4;  // + g*640 + j*16

    f32x4 acc[2][4];
#pragma unroll
    for (int mi = 0; mi < 2; ++mi)
#pragma unroll
        for (int nt = 0; nt < 4; ++nt) acc[mi][nt] = (f32x4){0.f, 0.f, 0.f, 0.f};

    f32x4 aR[4][4];   // [slot][g*2+j]
    i32x4 BF[2][4];   // [phase][nt]

    // ---- prologue: fill pipeline (tiles 0..5 of 64) ----
#pragma unroll
    for (int s = 0; s < 4; ++s)
#pragma unroll
        for (int g = 0; g < 2; ++g)
#pragma unroll
            for (int j = 0; j < 2; ++j)
                aR[s][g * 2 + j] = *(const f32x4*)(aGr[g] + s * 32 + j * 16);
#pragma unroll
    for (int nt = 0; nt < 4; ++nt) BF[0][nt] = *(const i32x4*)bpB[nt];
#pragma unroll
    for (int s = 0; s < 2; ++s) {
        unsigned short* wb = Aw + s * 1280;
#pragma unroll
        for (int g = 0; g < 2; ++g)
#pragma unroll
            for (int j = 0; j < 2; ++j)
                *(s16x4*)(wb + g * 640 + j * 16 + woff) = cvt4(aR[s][g * 2 + j]);
#pragma unroll
        for (int g = 0; g < 2; ++g)
#pragma unroll
            for (int j = 0; j < 2; ++j)
                aR[s][g * 2 + j] = *(const f32x4*)(aGr[g] + (4 + s) * 32 + j * 16);
    }

#define ROUND(qv, PH)                                                         \
    {                                                                         \
        /* B prefetch tile qv+1 */                                            \
        const int tB = (qv + 1) & 63;                                         \
        _Pragma("unroll") for (int nt = 0; nt < 4; ++nt)                      \
            BF[(PH + 1) & 1][nt] = *(const i32x4*)(bpB[nt] + (size_t)tB * 512); \
        /* cvt + LDS-write tile qv+2 (slot/buf (PH+2)&3) */                   \
        {                                                                     \
            unsigned short* wb = Aw + ((PH + 2) & 3) * 1280;                  \
            _Pragma("unroll") for (int g = 0; g < 2; ++g)                     \
                _Pragma("unroll") for (int j = 0; j < 2; ++j)                 \
                    *(s16x4*)(wb + g * 640 + j * 16 + woff) =                 \
                        cvt4(aR[(PH + 2) & 3][g * 2 + j]);                    \
        }                                                                     \
        /* A global load tile qv+6 into freed slot */                         \
        {                                                                     \
            const int ko = ((qv + 6) & 63) * 32;                              \
            _Pragma("unroll") for (int g = 0; g < 2; ++g)                     \
                _Pragma("unroll") for (int j = 0; j < 2; ++j)                 \
                    aR[(PH + 2) & 3][g * 2 + j] =                             \
                        *(const f32x4*)(aGr[g] + ko + j * 16);                \
        }                                                                     \
        /* frags + 8 MFMA */                                                  \
        {                                                                     \
            const unsigned short* rb = Aw + (PH & 3) * 1280;                  \
            s16x8 af0 = *(const s16x8*)(rb + t16 * 40 + quad * 8);            \
            s16x8 af1 = *(const s16x8*)(rb + (16 + t16) * 40 + quad * 8);     \
            _Pragma("unroll") for (int nt = 0; nt < 4; ++nt) {                \
                s16x8 bf = __builtin_bit_cast(s16x8, BF[PH & 1][nt]);         \
                acc[0][nt] = __builtin_amdgcn_mfma_f32_16x16x32_bf16(         \
                    af0, bf, acc[0][nt], 0, 0, 0);                            \
                acc[1][nt] = __builtin_amdgcn_mfma_f32_16x16x32_bf16(         \
                    af1, bf, acc[1][nt], 0, 0, 0);                            \
            }                                                                 \
        }                                                                     \
    }

#pragma unroll 1
    for (int q = 0; q < 64; q += 4) {
        ROUND(q + 0, 0)
        ROUND(q + 1, 1)
        ROUND(q + 2, 2)
        ROUND(q + 3, 3)
    }
#undef ROUND

    // ---- epilogue: accumulate into pre-biased out ----
#pragma unroll
    for (int mi = 0; mi < 2; ++mi) {
        const int i0 = row0 + mi * 16 + quad * 4;
#pragma unroll
        for (int nt = 0; nt < 4; ++nt) {
            float* op = out + ((size_t)cg * NODE + i0) * OUTD + nt * 16 + t16;
#pragma unroll
            for (int rr = 0; rr < 4; ++rr)
                atomicAdd(op + (size_t)rr * OUTD, acc[mi][nt][rr]);
        }
    }
}

// ---------------------------------------------------------------------------
extern "C" void kernel_launch(void* const* d_in, const int* in_sizes, int n_in,
                              void* d_out, int out_size, void* d_ws, size_t ws_size,
                              hipStream_t stream) {
    const float* x     = (const float*)d_in[0];
    const float* adj   = (const float*)d_in[1];
    const float* nl_w  = (const float*)d_in[2];
    const float* nl_b  = (const float*)d_in[3];
    const float* w_out = (const float*)d_in[4];
    const float* b_out = (const float*)d_in[5];
    float* out = (float*)d_out;

    unsigned short* ybf = (unsigned short*)d_ws;                      // 4 MB
    float* bias2 = (float*)((char*)d_ws + (size_t)NCOL * NODE * 2);   // 64 fp32

    bias2_kernel<<<1, 256, 0, stream>>>(nl_b, w_out, b_out, bias2);
    init_out_kernel<<<2048, 256, 0, stream>>>(out, bias2);
    build_ybf_kernel<<<256, 256, 0, stream>>>(x, nl_w, w_out, ybf);
    gemm_adj_kernel<<<1024, 256, 0, stream>>>(adj, ybf, out);
}